// Round 10
// baseline (365.614 us; speedup 1.0000x reference)
//
#include <hip/hip_runtime.h>
#include <hip/hip_bf16.h>
#include <stdint.h>

// Problem constants: B=4, N=2048, D=1024, H=16, hd=64, NCTX=512
#define BATCH  4
#define NSEQ   2048
#define DMODEL 1024
#define NHEAD  16
#define HDIM   64
#define NCTXC  512

typedef unsigned short u16;
typedef __attribute__((ext_vector_type(8))) short bfrag;   // 8 bf16 = 4 VGPRs (MFMA A/B operand)
typedef __attribute__((ext_vector_type(4))) float facc;    // MFMA C/D operand

typedef __attribute__((address_space(3))) void lds_void;
typedef __attribute__((address_space(1))) void g_void;

__device__ __forceinline__ void gload16(const void* g, void* l) {
  __builtin_amdgcn_global_load_lds((const g_void*)g, (lds_void*)l, 16, 0, 0);
}

__device__ __forceinline__ u16 f2bf(float f) {
  union { float f; uint32_t u; } un; un.f = f;
  uint32_t u = un.u;
  u += 0x7fffu + ((u >> 16) & 1u);   // RNE
  return (u16)(u >> 16);
}

#if __has_builtin(__builtin_amdgcn_cvt_pk_bf16_f32)
__device__ __forceinline__ uint32_t pk2bf(float a, float b) {
  return __builtin_bit_cast(uint32_t, __builtin_amdgcn_cvt_pk_bf16_f32(a, b));
}
#else
__device__ __forceinline__ uint32_t pk2bf(float a, float b) {
  return (uint32_t)f2bf(a) | ((uint32_t)f2bf(b) << 16);
}
#endif

__device__ __forceinline__ float bf2f(u16 h) {
  union { uint32_t u; float f; } un;
  un.u = ((uint32_t)h) << 16;
  return un.f;
}

__device__ __forceinline__ float load_flex(const void* p, size_t idx, int isb) {
  return isb ? bf2f(((const u16*)p)[idx]) : ((const float*)p)[idx];
}

__device__ __forceinline__ uint4 pack8(float4 a, float4 b) {
  uint4 r;
  r.x = pk2bf(a.x, a.y);
  r.y = pk2bf(a.z, a.w);
  r.z = pk2bf(b.x, b.y);
  r.w = pk2bf(b.z, b.w);
  return r;
}

// ---------------------------------------------------------------- dtype detector
__global__ __launch_bounds__(256) void detect_kernel(const u16* __restrict__ xraw,
                                                     int* __restrict__ flag) {
  __shared__ int s_high, s_zero;
  if (threadIdx.x == 0) { s_high = 0; s_zero = 0; }
  __syncthreads();
  int h = 0, z = 0;
  for (int i = threadIdx.x; i < 4096; i += 256) {
    const u16 v = xraw[2 * i];
    const int e = (v >> 7) & 0xFF;
    if (e >= 0x90) h++;
    if (v == 0) z++;
  }
  atomicAdd(&s_high, h);
  atomicAdd(&s_zero, z);
  __syncthreads();
  if (threadIdx.x == 0) flag[0] = (s_high < 64 && s_zero < 2048) ? 1 : 0;
}

// ---------------------------------------------------------------- prep kernels

__global__ __launch_bounds__(256) void cast_x_kernel(const void* __restrict__ x,
                                                     u16* __restrict__ xb,
                                                     const int* __restrict__ flag) {
  const int isb = flag[0];
  const int i = blockIdx.x * 256 + threadIdx.x;
  if (isb) {
    ((uint4*)xb)[i] = ((const uint4*)x)[i];
  } else {
    const float4 f0 = ((const float4*)x)[2 * i];
    const float4 f1 = ((const float4*)x)[2 * i + 1];
    ((uint4*)xb)[i] = pack8(f0, f1);
  }
}

__global__ __launch_bounds__(256) void transpose_flex(const void* __restrict__ W,
                                                      u16* __restrict__ Wt,
                                                      int R, int C,
                                                      const int* __restrict__ flag) {
  __shared__ float tile[32][33];
  const int isb = flag[0];
  const int tx = threadIdx.x;
  const int ty = threadIdx.y;
  const int c0 = blockIdx.x * 32;
  const int r0 = blockIdx.y * 32;
#pragma unroll
  for (int j = 0; j < 32; j += 8)
    tile[ty + j][tx] = load_flex(W, (size_t)(r0 + ty + j) * C + c0 + tx, isb);
  __syncthreads();
#pragma unroll
  for (int j = 0; j < 32; j += 8)
    Wt[(size_t)(c0 + ty + j) * R + r0 + tx] = f2bf(tile[tx][ty + j]);
}

// fused small preps; cbias pre-scaled by log2(e) for exp2-domain softmax
__global__ __launch_bounds__(256) void prep_small(const void* __restrict__ b_in,
                                                  const void* __restrict__ b_out,
                                                  const void* __restrict__ ppr,
                                                  const void* __restrict__ trust,
                                                  const void* __restrict__ alpha_p,
                                                  const void* __restrict__ ts_p,
                                                  float* __restrict__ bin_f,
                                                  float* __restrict__ bout_f,
                                                  float* __restrict__ gate,
                                                  float* __restrict__ cbias,
                                                  const int* __restrict__ flag) {
  const int isb = flag[0];
  const int i = blockIdx.x * 256 + threadIdx.x;
  if (i < 3072) {
    bin_f[i] = load_flex(b_in, i, isb);
  } else if (i < 4096) {
    bout_f[i - 3072] = load_flex(b_out, i - 3072, isb);
  } else if (i < 4096 + BATCH * NCTXC) {
    const int j = i - 4096;
    const float ts = load_flex(ts_p, 0, isb), al = load_flex(alpha_p, 0, isb);
    gate[j]  = 1.0f / (1.0f + __expf(-ts * load_flex(trust, j, isb)));
    cbias[j] = -al * logf(fmaxf(load_flex(ppr, j, isb), 1e-8f)) * 1.44269504f;
  }
}

// ---------------------------------------------------------------- GEMM (m97 async staging)
// EPI=0: QK projection -> qk (ldc=2048), +b_in; Q cols (bn<8) pre-scaled by 0.125*log2e.
// EPI=1: A = attn-out in qk Q-plane (lda=2048), +b_out, store d_out (dtype per flag).
template <int EPI>
__global__ __launch_bounds__(256) void gemm_bt(const u16* __restrict__ A,
                                               const u16* __restrict__ Bt,
                                               const float* __restrict__ biasf,
                                               void* __restrict__ Cout,
                                               int K, int lda, int ldc,
                                               const int* __restrict__ flag) {
  __shared__ u16 As[128 * 32];
  __shared__ u16 Bs[128 * 32];
  const int isb  = flag[0];
  const int tid  = threadIdx.x;
  const int w    = tid >> 6;
  const int lane = tid & 63;
  const int quad = lane >> 4;
  const int l16  = lane & 15;
  const int wM   = (w >> 1) * 64;
  const int wN   = (w & 1) * 64;
  const int bm   = blockIdx.y;
  const int bn   = blockIdx.x;

  facc acc[4][4] = {};

  const int srow  = tid >> 2;
  const int spart = tid & 3;
  const u16* Ag = A + (size_t)(bm * 128 + srow) * lda + spart * 8;
  const u16* Bg = Bt + (size_t)(bn * 128 + srow) * K + spart * 8;
  char* ldsA = (char*)As + tid * 16;
  char* ldsB = (char*)Bs + tid * 16;

  for (int k0 = 0; k0 < K; k0 += 32) {
    __syncthreads();
    gload16(Ag + k0, ldsA);
    gload16(Ag + (size_t)64 * lda + k0, ldsA + 4096);
    gload16(Bg + k0, ldsB);
    gload16(Bg + (size_t)64 * K + k0, ldsB + 4096);
    __syncthreads();

    bfrag af[4], bf[4];
#pragma unroll
    for (int i = 0; i < 4; ++i)
      af[i] = *(const bfrag*)(&As[(wM + i * 16 + l16) * 32 + quad * 8]);
#pragma unroll
    for (int j = 0; j < 4; ++j)
      bf[j] = *(const bfrag*)(&Bs[(wN + j * 16 + l16) * 32 + quad * 8]);
#pragma unroll
    for (int i = 0; i < 4; ++i)
#pragma unroll
      for (int j = 0; j < 4; ++j)
        acc[i][j] = __builtin_amdgcn_mfma_f32_16x16x32_bf16(af[i], bf[j], acc[i][j], 0, 0, 0);
  }

  const float qs = (EPI == 0 && bn < 8) ? 0.18033688f : 1.0f;

#pragma unroll
  for (int i = 0; i < 4; ++i) {
    const int grow0 = bm * 128 + wM + i * 16 + quad * 4;
#pragma unroll
    for (int j = 0; j < 4; ++j) {
      const int gcol = bn * 128 + wN + j * 16 + l16;
      const float bv = biasf[gcol];
#pragma unroll
      for (int r = 0; r < 4; ++r) {
        const int grow = grow0 + r;
        const float v = (acc[i][j][r] + bv) * qs;
        if (EPI == 0) {
          ((u16*)Cout)[(size_t)grow * ldc + gcol] = f2bf(v);
        } else {
          if (isb) ((u16*)Cout)[(size_t)grow * ldc + gcol] = f2bf(v);
          else     ((float*)Cout)[(size_t)grow * ldc + gcol] = v;
        }
      }
    }
  }
}

// ---------------------------------------------------------------- V^T GEMM (C^T trick)
// V^T[d][token]: A = Wt rows 2048..3071, Bt = xb. Coalesced Vtg stores (l16 = token).
__global__ __launch_bounds__(256) void gemm_vt(const u16* __restrict__ A,
                                               const u16* __restrict__ Bt,
                                               const float* __restrict__ biasf,
                                               const float* __restrict__ gate,
                                               u16* __restrict__ Vtg,
                                               int K) {
  __shared__ u16 As[128 * 32];
  __shared__ u16 Bs[128 * 32];
  const int tid  = threadIdx.x;
  const int w    = tid >> 6;
  const int lane = tid & 63;
  const int quad = lane >> 4;
  const int l16  = lane & 15;
  const int wM   = (w >> 1) * 64;
  const int wN   = (w & 1) * 64;
  const int bm   = blockIdx.y;   // 0..7   (d tiles)
  const int bn   = blockIdx.x;   // 0..63  (token tiles)

  facc acc[4][4] = {};

  const int srow  = tid >> 2;
  const int spart = tid & 3;
  const u16* Ag = A + (size_t)(bm * 128 + srow) * K + spart * 8;
  const u16* Bg = Bt + (size_t)(bn * 128 + srow) * K + spart * 8;
  char* ldsA = (char*)As + tid * 16;
  char* ldsB = (char*)Bs + tid * 16;

  for (int k0 = 0; k0 < K; k0 += 32) {
    __syncthreads();
    gload16(Ag + k0, ldsA);
    gload16(Ag + (size_t)64 * K + k0, ldsA + 4096);
    gload16(Bg + k0, ldsB);
    gload16(Bg + (size_t)64 * K + k0, ldsB + 4096);
    __syncthreads();

    bfrag af[4], bf[4];
#pragma unroll
    for (int i = 0; i < 4; ++i)
      af[i] = *(const bfrag*)(&As[(wM + i * 16 + l16) * 32 + quad * 8]);
#pragma unroll
    for (int j = 0; j < 4; ++j)
      bf[j] = *(const bfrag*)(&Bs[(wN + j * 16 + l16) * 32 + quad * 8]);
#pragma unroll
    for (int i = 0; i < 4; ++i)
#pragma unroll
      for (int j = 0; j < 4; ++j)
        acc[i][j] = __builtin_amdgcn_mfma_f32_16x16x32_bf16(af[i], bf[j], acc[i][j], 0, 0, 0);
  }

#pragma unroll
  for (int i = 0; i < 4; ++i) {
    const int grow0 = bm * 128 + wM + i * 16 + quad * 4;
    const int h   = grow0 >> 6;
    const int dd0 = grow0 & 63;
#pragma unroll
    for (int j = 0; j < 4; ++j) {
      const int gcol = bn * 128 + wN + j * 16 + l16;
      const int bb  = gcol >> 11;
      const int tok = gcol & (NSEQ - 1);
      const float gl = (tok < NCTXC) ? gate[bb * NCTXC + tok] : 1.0f;
      u16* dst = &Vtg[((size_t)((bb * NHEAD + h) * HDIM + dd0)) * NSEQ + tok];
#pragma unroll
      for (int r = 0; r < 4; ++r) {
        const float v = (acc[i][j][r] + biasf[2 * DMODEL + grow0 + r]) * gl;
        dst[(size_t)r * NSEQ] = f2bf(v);
      }
    }
  }
}

// ---------------------------------------------------------------- flash attention
// 128-q blocks, S^T form, static softmax (exp2 domain), pipelined K/V prefetch.
// Wave w owns q cols (w*2+qs)*16 + l16, qs=0,1. K (ak) AND V (av) fragments held in
// registers across both q-subtiles -> LDS reads per iter: 16 (K/V) + 2*2 (P) per wave
// for 32 q, vs 18 per 16 q before (44% less LDS read traffic per q).
__global__ __launch_bounds__(256) void attn_kernel(u16* __restrict__ qk,
                                                   const u16* __restrict__ vtg,
                                                   const float* __restrict__ cbias) {
  const int qt = blockIdx.x, h = blockIdx.y, b = blockIdx.z;
  __shared__ u16 Ks[64 * 72];        // K tile [kv][d]
  __shared__ u16 Vt[64 * 72];        // V^T tile [d][kv]
  __shared__ u16 Ps[4 * 16 * 72];    // per-wave P [q16][kv], wave-private, reused per qs

  const int tid  = threadIdx.x;
  const int w    = tid >> 6;
  const int lane = tid & 63;
  const int quad = lane >> 4;
  const int l16  = lane & 15;
  const int srow = tid >> 2;
  const int spart = tid & 3;

  // Q fragments for both subtiles (Q pre-scaled into exp2 domain by GEMM epilogue)
  bfrag bq[2][2];
#pragma unroll
  for (int qs = 0; qs < 2; ++qs) {
    const u16* qrow = qk + (size_t)(b * NSEQ + qt * 128 + (w * 2 + qs) * 16 + l16) * 2048 + h * HDIM;
    bq[qs][0] = *(const bfrag*)(qrow + quad * 8);
    bq[qs][1] = *(const bfrag*)(qrow + 32 + quad * 8);
  }

  float l_i[2] = {0.0f, 0.0f};
  facc o[2][4] = {};

  const u16* kst = qk + (size_t)(b * NSEQ) * 2048 + DMODEL + h * HDIM;
  const u16* vst = vtg + (size_t)((b * NHEAD + h) * HDIM + srow) * NSEQ;
  u16* psw = &Ps[w * 16 * 72];

  uint4 pk0, pk1, pv0, pv1;
  {
    const u16* ks = kst + (size_t)srow * 2048 + spart * 16;
    pk0 = *(const uint4*)ks;
    pk1 = *(const uint4*)(ks + 8);
    const u16* vs = vst + spart * 16;
    pv0 = *(const uint4*)vs;
    pv1 = *(const uint4*)(vs + 8);
  }

  for (int t = 0; t < NSEQ / 64; ++t) {
    __syncthreads();
    *(uint4*)(&Ks[srow * 72 + spart * 16])     = pk0;
    *(uint4*)(&Ks[srow * 72 + spart * 16 + 8]) = pk1;
    *(uint4*)(&Vt[srow * 72 + spart * 16])     = pv0;
    *(uint4*)(&Vt[srow * 72 + spart * 16 + 8]) = pv1;
    __syncthreads();

    // prefetch next K/V tile
    {
      const int tn = (t < NSEQ / 64 - 1) ? t + 1 : t;
      const u16* ks = kst + (size_t)(tn * 64 + srow) * 2048 + spart * 16;
      pk0 = *(const uint4*)ks;
      pk1 = *(const uint4*)(ks + 8);
      const u16* vs = vst + tn * 64 + spart * 16;
      pv0 = *(const uint4*)vs;
      pv1 = *(const uint4*)(vs + 8);
    }

    // K and V fragments once per tile, held across both q-subtiles
    bfrag ak[4][2], av[4][2];
#pragma unroll
    for (int nt = 0; nt < 4; ++nt) {
      ak[nt][0] = *(const bfrag*)(&Ks[(nt * 16 + l16) * 72 + quad * 8]);
      ak[nt][1] = *(const bfrag*)(&Ks[(nt * 16 + l16) * 72 + 32 + quad * 8]);
      av[nt][0] = *(const bfrag*)(&Vt[(nt * 16 + l16) * 72 + quad * 8]);
      av[nt][1] = *(const bfrag*)(&Vt[(nt * 16 + l16) * 72 + 32 + quad * 8]);
    }

#pragma unroll
    for (int qs = 0; qs < 2; ++qs) {
      facc s[4];
#pragma unroll
      for (int nt = 0; nt < 4; ++nt) {
        facc z = {};
        z = __builtin_amdgcn_mfma_f32_16x16x32_bf16(ak[nt][0], bq[qs][0], z, 0, 0, 0);
        s[nt] = __builtin_amdgcn_mfma_f32_16x16x32_bf16(ak[nt][1], bq[qs][1], z, 0, 0, 0);
      }

      // static softmax: p = exp2(s [+ cbias_pre]); kv = t*64+nt*16+quad*4+r
      float rs = 0.0f;
      if (t < 8) {
        const float* cb = cbias + b * NCTXC + t * 64 + quad * 4;
#pragma unroll
        for (int nt = 0; nt < 4; ++nt)
#pragma unroll
          for (int r = 0; r < 4; ++r) {
            const float p = __builtin_amdgcn_exp2f(s[nt][r] + cb[nt * 16 + r]);
            s[nt][r] = p;
            rs += p;
          }
      } else {
#pragma unroll
        for (int nt = 0; nt < 4; ++nt)
#pragma unroll
          for (int r = 0; r < 4; ++r) {
            const float p = __builtin_amdgcn_exp2f(s[nt][r]);
            s[nt][r] = p;
            rs += p;
          }
      }
      rs += __shfl_xor(rs, 16);
      rs += __shfl_xor(rs, 32);
      l_i[qs] += rs;

      // P -> wave-private Ps (reused per qs; in-order DS pipe keeps read-before-write)
#pragma unroll
      for (int nt = 0; nt < 4; ++nt) {
        uint2 pk;
        pk.x = pk2bf(s[nt][0], s[nt][1]);
        pk.y = pk2bf(s[nt][2], s[nt][3]);
        *(uint2*)(&psw[l16 * 72 + nt * 16 + quad * 4]) = pk;
      }

      __asm__ volatile("s_waitcnt lgkmcnt(0)" ::: "memory");

      const bfrag bp0 = *(const bfrag*)(&psw[l16 * 72 + quad * 8]);
      const bfrag bp1 = *(const bfrag*)(&psw[l16 * 72 + 32 + quad * 8]);
#pragma unroll
      for (int dt = 0; dt < 4; ++dt) {
        o[qs][dt] = __builtin_amdgcn_mfma_f32_16x16x32_bf16(av[dt][0], bp0, o[qs][dt], 0, 0, 0);
        o[qs][dt] = __builtin_amdgcn_mfma_f32_16x16x32_bf16(av[dt][1], bp1, o[qs][dt], 0, 0, 0);
      }
    }
  }

  // O^T C-layout: col=l16=q, row=quad*4+r=d -> pack 4 consecutive d
#pragma unroll
  for (int qs = 0; qs < 2; ++qs) {
    const float inv = 1.0f / l_i[qs];
    u16* orow = qk + (size_t)(b * NSEQ + qt * 128 + (w * 2 + qs) * 16 + l16) * 2048 + h * HDIM;
#pragma unroll
    for (int dt = 0; dt < 4; ++dt) {
      uint2 st;
      st.x = pk2bf(o[qs][dt][0] * inv, o[qs][dt][1] * inv);
      st.y = pk2bf(o[qs][dt][2] * inv, o[qs][dt][3] * inv);
      *(uint2*)(orow + dt * 16 + quad * 4) = st;
    }
  }
}

// ---------------------------------------------------------------- launch

extern "C" void kernel_launch(void* const* d_in, const int* in_sizes, int n_in,
                              void* d_out, int out_size, void* d_ws, size_t ws_size,
                              hipStream_t stream) {
  const void* x          = d_in[0];
  const void* ctx_ppr    = d_in[1];
  const void* ctx_trust  = d_in[2];
  const void* W_in       = d_in[3];
  const void* b_in       = d_in[4];
  const void* W_out      = d_in[5];
  const void* b_out      = d_in[6];
  const void* lppr_alpha = d_in[7];
  const void* tscale     = d_in[8];

  char* ws = (char*)d_ws;
  u16* Wt    = (u16*)ws;  ws += (size_t)3072 * 1024 * 2;    //  6 MB  W_in^T bf16
  u16* WoT   = (u16*)ws;  ws += (size_t)1024 * 1024 * 2;    //  2 MB  W_out^T bf16
  u16* qk    = (u16*)ws;  ws += (size_t)8192 * 2048 * 2;    // 32 MB  [Q|K]; attn-out overwrites Q-plane
  u16* Vtg   = (u16*)ws;  ws += (size_t)64 * 64 * 2048 * 2; // 16 MB  gated V^T [b*16+h][d][n]
  u16* xb    = (u16*)ws;  ws += (size_t)8192 * 1024 * 2;    // 16 MB  x as bf16
  float* bin_f  = (float*)ws; ws += 3072 * 4;
  float* bout_f = (float*)ws; ws += 1024 * 4;
  float* gate   = (float*)ws; ws += (size_t)BATCH * NCTXC * 4;
  float* cbias  = (float*)ws; ws += (size_t)BATCH * NCTXC * 4;
  int*   flag   = (int*)ws;   ws += 64;

  detect_kernel<<<dim3(1), dim3(256), 0, stream>>>((const u16*)x, flag);
  cast_x_kernel<<<dim3(4096), dim3(256), 0, stream>>>(x, xb, flag);
  transpose_flex<<<dim3(96, 32), dim3(32, 8), 0, stream>>>(W_in, Wt, 1024, 3072, flag);
  transpose_flex<<<dim3(32, 32), dim3(32, 8), 0, stream>>>(W_out, WoT, 1024, 1024, flag);
  prep_small<<<dim3(24), dim3(256), 0, stream>>>(b_in, b_out, ctx_ppr, ctx_trust,
                                                 lppr_alpha, tscale,
                                                 bin_f, bout_f, gate, cbias, flag);
  // QK GEMM: [8192x1024] @ [1024x2048] (+b_in, Q pre-scaled) -> qk
  gemm_bt<0><<<dim3(16, 64), dim3(256), 0, stream>>>(xb, Wt, bin_f, (void*)qk,
                                                     1024, 1024, 2048, flag);
  // V^T GEMM: C^T trick (+b_in[2048+], gated) -> Vtg coalesced
  gemm_vt<<<dim3(64, 8), dim3(256), 0, stream>>>(Wt + (size_t)2048 * 1024, xb, bin_f, gate,
                                                 Vtg, 1024);
  // fused biased attention (128-q blocks, K+V frags in regs), output into qk Q-plane
  attn_kernel<<<dim3(16, 16, 4), dim3(256), 0, stream>>>(qk, Vtg, cbias);
  // output GEMM: [8192x1024 (lda 2048)] @ [1024x1024] (+b_out) -> d_out
  gemm_bt<1><<<dim3(8, 64), dim3(256), 0, stream>>>(qk, WoT, bout_f,
                                                    d_out, 1024, 2048, 1024, flag);
}

// Round 11
// 338.369 us; speedup vs baseline: 1.0805x; 1.0805x over previous
//
#include <hip/hip_runtime.h>
#include <hip/hip_bf16.h>
#include <stdint.h>

// Problem constants: B=4, N=2048, D=1024, H=16, hd=64, NCTX=512
#define BATCH  4
#define NSEQ   2048
#define DMODEL 1024
#define NHEAD  16
#define HDIM   64
#define NCTXC  512

typedef unsigned short u16;
typedef __attribute__((ext_vector_type(8))) short bfrag;   // 8 bf16 = 4 VGPRs (MFMA A/B operand)
typedef __attribute__((ext_vector_type(4))) float facc;    // MFMA C/D operand

typedef __attribute__((address_space(3))) void lds_void;
typedef __attribute__((address_space(1))) void g_void;

__device__ __forceinline__ void gload16(const void* g, void* l) {
  __builtin_amdgcn_global_load_lds((const g_void*)g, (lds_void*)l, 16, 0, 0);
}

__device__ __forceinline__ u16 f2bf(float f) {
  union { float f; uint32_t u; } un; un.f = f;
  uint32_t u = un.u;
  u += 0x7fffu + ((u >> 16) & 1u);   // RNE
  return (u16)(u >> 16);
}

#if __has_builtin(__builtin_amdgcn_cvt_pk_bf16_f32)
__device__ __forceinline__ uint32_t pk2bf(float a, float b) {
  return __builtin_bit_cast(uint32_t, __builtin_amdgcn_cvt_pk_bf16_f32(a, b));
}
#else
__device__ __forceinline__ uint32_t pk2bf(float a, float b) {
  return (uint32_t)f2bf(a) | ((uint32_t)f2bf(b) << 16);
}
#endif

__device__ __forceinline__ float bf2f(u16 h) {
  union { uint32_t u; float f; } un;
  un.u = ((uint32_t)h) << 16;
  return un.f;
}

__device__ __forceinline__ float load_flex(const void* p, size_t idx, int isb) {
  return isb ? bf2f(((const u16*)p)[idx]) : ((const float*)p)[idx];
}

__device__ __forceinline__ uint4 pack8(float4 a, float4 b) {
  uint4 r;
  r.x = pk2bf(a.x, a.y);
  r.y = pk2bf(a.z, a.w);
  r.z = pk2bf(b.x, b.y);
  r.w = pk2bf(b.z, b.w);
  return r;
}

// ---------------------------------------------------------------- dtype detector
__global__ __launch_bounds__(256) void detect_kernel(const u16* __restrict__ xraw,
                                                     int* __restrict__ flag) {
  __shared__ int s_high, s_zero;
  if (threadIdx.x == 0) { s_high = 0; s_zero = 0; }
  __syncthreads();
  int h = 0, z = 0;
  for (int i = threadIdx.x; i < 4096; i += 256) {
    const u16 v = xraw[2 * i];
    const int e = (v >> 7) & 0xFF;
    if (e >= 0x90) h++;
    if (v == 0) z++;
  }
  atomicAdd(&s_high, h);
  atomicAdd(&s_zero, z);
  __syncthreads();
  if (threadIdx.x == 0) flag[0] = (s_high < 64 && s_zero < 2048) ? 1 : 0;
}

// ---------------------------------------------------------------- prep kernels

__global__ __launch_bounds__(256) void cast_x_kernel(const void* __restrict__ x,
                                                     u16* __restrict__ xb,
                                                     const int* __restrict__ flag) {
  const int isb = flag[0];
  const int i = blockIdx.x * 256 + threadIdx.x;
  if (isb) {
    ((uint4*)xb)[i] = ((const uint4*)x)[i];
  } else {
    const float4 f0 = ((const float4*)x)[2 * i];
    const float4 f1 = ((const float4*)x)[2 * i + 1];
    ((uint4*)xb)[i] = pack8(f0, f1);
  }
}

__global__ __launch_bounds__(256) void transpose_flex(const void* __restrict__ W,
                                                      u16* __restrict__ Wt,
                                                      int R, int C,
                                                      const int* __restrict__ flag) {
  __shared__ float tile[32][33];
  const int isb = flag[0];
  const int tx = threadIdx.x;
  const int ty = threadIdx.y;
  const int c0 = blockIdx.x * 32;
  const int r0 = blockIdx.y * 32;
#pragma unroll
  for (int j = 0; j < 32; j += 8)
    tile[ty + j][tx] = load_flex(W, (size_t)(r0 + ty + j) * C + c0 + tx, isb);
  __syncthreads();
#pragma unroll
  for (int j = 0; j < 32; j += 8)
    Wt[(size_t)(c0 + ty + j) * R + r0 + tx] = f2bf(tile[tx][ty + j]);
}

// fused small preps; cbias pre-scaled by log2(e) for exp2-domain softmax
__global__ __launch_bounds__(256) void prep_small(const void* __restrict__ b_in,
                                                  const void* __restrict__ b_out,
                                                  const void* __restrict__ ppr,
                                                  const void* __restrict__ trust,
                                                  const void* __restrict__ alpha_p,
                                                  const void* __restrict__ ts_p,
                                                  float* __restrict__ bin_f,
                                                  float* __restrict__ bout_f,
                                                  float* __restrict__ gate,
                                                  float* __restrict__ cbias,
                                                  const int* __restrict__ flag) {
  const int isb = flag[0];
  const int i = blockIdx.x * 256 + threadIdx.x;
  if (i < 3072) {
    bin_f[i] = load_flex(b_in, i, isb);
  } else if (i < 4096) {
    bout_f[i - 3072] = load_flex(b_out, i - 3072, isb);
  } else if (i < 4096 + BATCH * NCTXC) {
    const int j = i - 4096;
    const float ts = load_flex(ts_p, 0, isb), al = load_flex(alpha_p, 0, isb);
    gate[j]  = 1.0f / (1.0f + __expf(-ts * load_flex(trust, j, isb)));
    cbias[j] = -al * logf(fmaxf(load_flex(ppr, j, isb), 1e-8f)) * 1.44269504f;
  }
}

// ---------------------------------------------------------------- shared K-loop (m97 staging)
__device__ __forceinline__ void kloop_mfma(const u16* __restrict__ Ag,
                                           const u16* __restrict__ Bg,
                                           u16* As, u16* Bs,
                                           int tid, int wM, int wN, int l16, int quad,
                                           facc acc[4][4]) {
  char* ldsA = (char*)As + tid * 16;
  char* ldsB = (char*)Bs + tid * 16;
  for (int k0 = 0; k0 < 1024; k0 += 32) {
    __syncthreads();
    gload16(Ag + k0, ldsA);
    gload16(Ag + (size_t)64 * 1024 + k0, ldsA + 4096);
    gload16(Bg + k0, ldsB);
    gload16(Bg + (size_t)64 * 1024 + k0, ldsB + 4096);
    __syncthreads();

    bfrag af[4], bf[4];
#pragma unroll
    for (int i = 0; i < 4; ++i)
      af[i] = *(const bfrag*)(&As[(wM + i * 16 + l16) * 32 + quad * 8]);
#pragma unroll
    for (int j = 0; j < 4; ++j)
      bf[j] = *(const bfrag*)(&Bs[(wN + j * 16 + l16) * 32 + quad * 8]);
#pragma unroll
    for (int i = 0; i < 4; ++i)
#pragma unroll
      for (int j = 0; j < 4; ++j)
        acc[i][j] = __builtin_amdgcn_mfma_f32_16x16x32_bf16(af[i], bf[j], acc[i][j], 0, 0, 0);
  }
}

// ---------------------------------------------------------------- merged QK + V^T GEMM
// blocks 0..1023: QK projection (bn=id&15, bm=id>>4) -> qk (ldc=2048), +b_in,
//                 Q cols (bn<8) pre-scaled by 0.125*log2e.
// blocks 1024..1535: V^T via C^T trick (bn=(id-1024)&63 token tiles, bm=(id-1024)>>6 d tiles)
//                 -> Vtg[(b*16+h)*64+d][token], +b_in[2048+d], trust-gated, coalesced.
__global__ __launch_bounds__(256) void gemm_qkvt(const u16* __restrict__ xb,
                                                 const u16* __restrict__ Wt,
                                                 const float* __restrict__ bin_f,
                                                 const float* __restrict__ gate,
                                                 u16* __restrict__ qk,
                                                 u16* __restrict__ Vtg) {
  __shared__ u16 As[128 * 32];
  __shared__ u16 Bs[128 * 32];
  const int tid  = threadIdx.x;
  const int w    = tid >> 6;
  const int lane = tid & 63;
  const int quad = lane >> 4;
  const int l16  = lane & 15;
  const int wM   = (w >> 1) * 64;
  const int wN   = (w & 1) * 64;
  const int id   = blockIdx.x;
  const int srow  = tid >> 2;
  const int spart = tid & 3;

  facc acc[4][4] = {};

  if (id < 1024) {
    const int bn = id & 15, bm = id >> 4;
    const u16* Ag = xb + (size_t)(bm * 128 + srow) * 1024 + spart * 8;
    const u16* Bg = Wt + (size_t)(bn * 128 + srow) * 1024 + spart * 8;
    kloop_mfma(Ag, Bg, As, Bs, tid, wM, wN, l16, quad, acc);

    const float qs = (bn < 8) ? 0.18033688f : 1.0f;
#pragma unroll
    for (int i = 0; i < 4; ++i) {
      const int grow0 = bm * 128 + wM + i * 16 + quad * 4;
#pragma unroll
      for (int j = 0; j < 4; ++j) {
        const int gcol = bn * 128 + wN + j * 16 + l16;
        const float bv = bin_f[gcol];
#pragma unroll
        for (int r = 0; r < 4; ++r)
          qk[(size_t)(grow0 + r) * 2048 + gcol] = f2bf((acc[i][j][r] + bv) * qs);
      }
    }
  } else {
    const int id2 = id - 1024;
    const int bn = id2 & 63, bm = id2 >> 6;
    const u16* Ag = Wt + (size_t)2048 * 1024 + (size_t)(bm * 128 + srow) * 1024 + spart * 8;
    const u16* Bg = xb + (size_t)(bn * 128 + srow) * 1024 + spart * 8;
    kloop_mfma(Ag, Bg, As, Bs, tid, wM, wN, l16, quad, acc);

#pragma unroll
    for (int i = 0; i < 4; ++i) {
      const int grow0 = bm * 128 + wM + i * 16 + quad * 4;
      const int h   = grow0 >> 6;
      const int dd0 = grow0 & 63;
#pragma unroll
      for (int j = 0; j < 4; ++j) {
        const int gcol = bn * 128 + wN + j * 16 + l16;
        const int bb  = gcol >> 11;
        const int tok = gcol & (NSEQ - 1);
        const float gl = (tok < NCTXC) ? gate[bb * NCTXC + tok] : 1.0f;
        u16* dst = &Vtg[((size_t)((bb * NHEAD + h) * HDIM + dd0)) * NSEQ + tok];
#pragma unroll
        for (int r = 0; r < 4; ++r)
          dst[(size_t)r * NSEQ] = f2bf((acc[i][j][r] + bin_f[2 * DMODEL + grow0 + r]) * gl);
      }
    }
  }
}

// ---------------------------------------------------------------- output GEMM (m97 staging)
__global__ __launch_bounds__(256) void gemm_out(const u16* __restrict__ A,
                                                const u16* __restrict__ Bt,
                                                const float* __restrict__ biasf,
                                                void* __restrict__ Cout,
                                                const int* __restrict__ flag) {
  __shared__ u16 As[128 * 32];
  __shared__ u16 Bs[128 * 32];
  const int isb  = flag[0];
  const int tid  = threadIdx.x;
  const int w    = tid >> 6;
  const int lane = tid & 63;
  const int quad = lane >> 4;
  const int l16  = lane & 15;
  const int wM   = (w >> 1) * 64;
  const int wN   = (w & 1) * 64;
  const int bm   = blockIdx.y;
  const int bn   = blockIdx.x;
  const int srow  = tid >> 2;
  const int spart = tid & 3;

  facc acc[4][4] = {};
  // A = attn-out in qk Q-plane: lda = 2048
  const u16* Ag = A + (size_t)(bm * 128 + srow) * 2048 + spart * 8;
  const u16* Bg = Bt + (size_t)(bn * 128 + srow) * 1024 + spart * 8;
  char* ldsA = (char*)As + tid * 16;
  char* ldsB = (char*)Bs + tid * 16;

  for (int k0 = 0; k0 < 1024; k0 += 32) {
    __syncthreads();
    gload16(Ag + k0, ldsA);
    gload16(Ag + (size_t)64 * 2048 + k0, ldsA + 4096);
    gload16(Bg + k0, ldsB);
    gload16(Bg + (size_t)64 * 1024 + k0, ldsB + 4096);
    __syncthreads();

    bfrag af[4], bf[4];
#pragma unroll
    for (int i = 0; i < 4; ++i)
      af[i] = *(const bfrag*)(&As[(wM + i * 16 + l16) * 32 + quad * 8]);
#pragma unroll
    for (int j = 0; j < 4; ++j)
      bf[j] = *(const bfrag*)(&Bs[(wN + j * 16 + l16) * 32 + quad * 8]);
#pragma unroll
    for (int i = 0; i < 4; ++i)
#pragma unroll
      for (int j = 0; j < 4; ++j)
        acc[i][j] = __builtin_amdgcn_mfma_f32_16x16x32_bf16(af[i], bf[j], acc[i][j], 0, 0, 0);
  }

#pragma unroll
  for (int i = 0; i < 4; ++i) {
    const int grow0 = bm * 128 + wM + i * 16 + quad * 4;
#pragma unroll
    for (int j = 0; j < 4; ++j) {
      const int gcol = bn * 128 + wN + j * 16 + l16;
      const float bv = biasf[gcol];
#pragma unroll
      for (int r = 0; r < 4; ++r) {
        const float v = acc[i][j][r] + bv;
        if (isb) ((u16*)Cout)[(size_t)(grow0 + r) * 1024 + gcol] = f2bf(v);
        else     ((float*)Cout)[(size_t)(grow0 + r) * 1024 + gcol] = v;
      }
    }
  }
}

// ---------------------------------------------------------------- flash attention
// 64-q blocks, S^T form, static softmax (exp2 domain), K/V global prefetch,
// and PV DEFERRED one iteration: PV(t-1) MFMAs issue right after QK(t), filling the
// matrix pipe while exp2(t) runs on the VALU. Vt double-buffered; bp (P frags) carried
// in registers across iterations.
__global__ __launch_bounds__(256) void attn_kernel(u16* __restrict__ qk,
                                                   const u16* __restrict__ vtg,
                                                   const float* __restrict__ cbias) {
  const int qt = blockIdx.x, h = blockIdx.y, b = blockIdx.z;
  __shared__ u16 Ks[64 * 72];        // K tile [kv][d]
  __shared__ u16 Vt[2][64 * 72];     // V^T tile [d][kv], double-buffered
  __shared__ u16 Ps[4 * 16 * 72];    // per-wave P [q16][kv], wave-private

  const int tid  = threadIdx.x;
  const int w    = tid >> 6;
  const int lane = tid & 63;
  const int quad = lane >> 4;
  const int l16  = lane & 15;
  const int srow = tid >> 2;
  const int spart = tid & 3;

  const u16* qrow = qk + (size_t)(b * NSEQ + qt * 64 + w * 16 + l16) * 2048 + h * HDIM;
  const bfrag bq0 = *(const bfrag*)(qrow + quad * 8);
  const bfrag bq1 = *(const bfrag*)(qrow + 32 + quad * 8);

  float l_i = 0.0f;
  facc o[4] = {};
  bfrag bp0, bp1;                    // P(t-1) fragments (valid for t >= 1)

  const u16* kst = qk + (size_t)(b * NSEQ) * 2048 + DMODEL + h * HDIM;
  const u16* vst = vtg + (size_t)((b * NHEAD + h) * HDIM + srow) * NSEQ;
  u16* psw = &Ps[w * 16 * 72];

  uint4 pk0, pk1, pv0, pv1;
  {
    const u16* ks = kst + (size_t)srow * 2048 + spart * 16;
    pk0 = *(const uint4*)ks;
    pk1 = *(const uint4*)(ks + 8);
    const u16* vs = vst + spart * 16;
    pv0 = *(const uint4*)vs;
    pv1 = *(const uint4*)(vs + 8);
  }

  for (int t = 0; t < NSEQ / 64; ++t) {
    __syncthreads();   // all reads of Ks(t-1)/Vt[t&1] (from iter t-2's PV) complete
    u16* vb = Vt[t & 1];
    *(uint4*)(&Ks[srow * 72 + spart * 16])     = pk0;
    *(uint4*)(&Ks[srow * 72 + spart * 16 + 8]) = pk1;
    *(uint4*)(&vb[srow * 72 + spart * 16])     = pv0;
    *(uint4*)(&vb[srow * 72 + spart * 16 + 8]) = pv1;
    __syncthreads();

    // prefetch next K/V tile (vmcnt wait lands at next iter's stores)
    {
      const int tn = (t < NSEQ / 64 - 1) ? t + 1 : t;
      const u16* ks = kst + (size_t)(tn * 64 + srow) * 2048 + spart * 16;
      pk0 = *(const uint4*)ks;
      pk1 = *(const uint4*)(ks + 8);
      const u16* vs = vst + tn * 64 + spart * 16;
      pv0 = *(const uint4*)vs;
      pv1 = *(const uint4*)(vs + 8);
    }

    // QK(t): S^T = K·Q^T
    facc s[4];
#pragma unroll
    for (int nt = 0; nt < 4; ++nt) {
      const bfrag ak0 = *(const bfrag*)(&Ks[(nt * 16 + l16) * 72 + quad * 8]);
      const bfrag ak1 = *(const bfrag*)(&Ks[(nt * 16 + l16) * 72 + 32 + quad * 8]);
      facc z = {};
      z = __builtin_amdgcn_mfma_f32_16x16x32_bf16(ak0, bq0, z, 0, 0, 0);
      s[nt] = __builtin_amdgcn_mfma_f32_16x16x32_bf16(ak1, bq1, z, 0, 0, 0);
    }

    // PV(t-1): independent of s(t) -> fills the matrix pipe during exp2(t)
    if (t > 0) {
      const u16* vp = Vt[(t - 1) & 1];
#pragma unroll
      for (int dt = 0; dt < 4; ++dt) {
        const bfrag av0 = *(const bfrag*)(&vp[(dt * 16 + l16) * 72 + quad * 8]);
        const bfrag av1 = *(const bfrag*)(&vp[(dt * 16 + l16) * 72 + 32 + quad * 8]);
        o[dt] = __builtin_amdgcn_mfma_f32_16x16x32_bf16(av0, bp0, o[dt], 0, 0, 0);
        o[dt] = __builtin_amdgcn_mfma_f32_16x16x32_bf16(av1, bp1, o[dt], 0, 0, 0);
      }
    }

    // static softmax: p = exp2(s [+ cbias_pre]); kv = t*64+nt*16+quad*4+r
    float rs = 0.0f;
    if (t < 8) {
      const float* cb = cbias + b * NCTXC + t * 64 + quad * 4;
#pragma unroll
      for (int nt = 0; nt < 4; ++nt)
#pragma unroll
        for (int r = 0; r < 4; ++r) {
          const float p = __builtin_amdgcn_exp2f(s[nt][r] + cb[nt * 16 + r]);
          s[nt][r] = p;
          rs += p;
        }
    } else {
#pragma unroll
      for (int nt = 0; nt < 4; ++nt)
#pragma unroll
        for (int r = 0; r < 4; ++r) {
          const float p = __builtin_amdgcn_exp2f(s[nt][r]);
          s[nt][r] = p;
          rs += p;
        }
    }
    rs += __shfl_xor(rs, 16);
    rs += __shfl_xor(rs, 32);
    l_i += rs;

    // P(t) -> wave-private Ps -> back into registers (A-layout frags for next iter)
#pragma unroll
    for (int nt = 0; nt < 4; ++nt) {
      uint2 pk;
      pk.x = pk2bf(s[nt][0], s[nt][1]);
      pk.y = pk2bf(s[nt][2], s[nt][3]);
      *(uint2*)(&psw[l16 * 72 + nt * 16 + quad * 4]) = pk;
    }
    __asm__ volatile("s_waitcnt lgkmcnt(0)" ::: "memory");
    bp0 = *(const bfrag*)(&psw[l16 * 72 + quad * 8]);
    bp1 = *(const bfrag*)(&psw[l16 * 72 + 32 + quad * 8]);
  }

  // drain: PV for the last tile
  {
    const u16* vp = Vt[(NSEQ / 64 - 1) & 1];
#pragma unroll
    for (int dt = 0; dt < 4; ++dt) {
      const bfrag av0 = *(const bfrag*)(&vp[(dt * 16 + l16) * 72 + quad * 8]);
      const bfrag av1 = *(const bfrag*)(&vp[(dt * 16 + l16) * 72 + 32 + quad * 8]);
      o[dt] = __builtin_amdgcn_mfma_f32_16x16x32_bf16(av0, bp0, o[dt], 0, 0, 0);
      o[dt] = __builtin_amdgcn_mfma_f32_16x16x32_bf16(av1, bp1, o[dt], 0, 0, 0);
    }
  }

  // O^T C-layout: col=l16=q, row=quad*4+r=d -> pack 4 consecutive d
  const float inv = 1.0f / l_i;
  u16* orow = qk + (size_t)(b * NSEQ + qt * 64 + w * 16 + l16) * 2048 + h * HDIM;
#pragma unroll
  for (int dt = 0; dt < 4; ++dt) {
    uint2 st;
    st.x = pk2bf(o[dt][0] * inv, o[dt][1] * inv);
    st.y = pk2bf(o[dt][2] * inv, o[dt][3] * inv);
    *(uint2*)(orow + dt * 16 + quad * 4) = st;
  }
}

// ---------------------------------------------------------------- launch

extern "C" void kernel_launch(void* const* d_in, const int* in_sizes, int n_in,
                              void* d_out, int out_size, void* d_ws, size_t ws_size,
                              hipStream_t stream) {
  const void* x          = d_in[0];
  const void* ctx_ppr    = d_in[1];
  const void* ctx_trust  = d_in[2];
  const void* W_in       = d_in[3];
  const void* b_in       = d_in[4];
  const void* W_out      = d_in[5];
  const void* b_out      = d_in[6];
  const void* lppr_alpha = d_in[7];
  const void* tscale     = d_in[8];

  char* ws = (char*)d_ws;
  u16* Wt    = (u16*)ws;  ws += (size_t)3072 * 1024 * 2;    //  6 MB  W_in^T bf16
  u16* WoT   = (u16*)ws;  ws += (size_t)1024 * 1024 * 2;    //  2 MB  W_out^T bf16
  u16* qk    = (u16*)ws;  ws += (size_t)8192 * 2048 * 2;    // 32 MB  [Q|K]; attn-out overwrites Q-plane
  u16* Vtg   = (u16*)ws;  ws += (size_t)64 * 64 * 2048 * 2; // 16 MB  gated V^T [b*16+h][d][n]
  u16* xb    = (u16*)ws;  ws += (size_t)8192 * 1024 * 2;    // 16 MB  x as bf16
  float* bin_f  = (float*)ws; ws += 3072 * 4;
  float* bout_f = (float*)ws; ws += 1024 * 4;
  float* gate   = (float*)ws; ws += (size_t)BATCH * NCTXC * 4;
  float* cbias  = (float*)ws; ws += (size_t)BATCH * NCTXC * 4;
  int*   flag   = (int*)ws;   ws += 64;

  detect_kernel<<<dim3(1), dim3(256), 0, stream>>>((const u16*)x, flag);
  cast_x_kernel<<<dim3(4096), dim3(256), 0, stream>>>(x, xb, flag);
  transpose_flex<<<dim3(96, 32), dim3(32, 8), 0, stream>>>(W_in, Wt, 1024, 3072, flag);
  transpose_flex<<<dim3(32, 32), dim3(32, 8), 0, stream>>>(W_out, WoT, 1024, 1024, flag);
  prep_small<<<dim3(24), dim3(256), 0, stream>>>(b_in, b_out, ctx_ppr, ctx_trust,
                                                 lppr_alpha, tscale,
                                                 bin_f, bout_f, gate, cbias, flag);
  // merged QK GEMM (1024 blocks) + V^T GEMM (512 blocks)
  gemm_qkvt<<<dim3(1536), dim3(256), 0, stream>>>(xb, Wt, bin_f, gate, qk, Vtg);
  // fused biased attention (PV deferred one iter), output into qk Q-plane
  attn_kernel<<<dim3(32, 16, 4), dim3(256), 0, stream>>>(qk, Vtg, cbias);
  // output GEMM: [8192x1024 (lda 2048)] @ [1024x1024] (+b_out) -> d_out
  gemm_out<<<dim3(8, 64), dim3(256), 0, stream>>>(qk, WoT, bout_f, d_out, flag);
}

// Round 12
// 334.142 us; speedup vs baseline: 1.0942x; 1.0127x over previous
//
#include <hip/hip_runtime.h>
#include <hip/hip_bf16.h>
#include <stdint.h>

// Problem constants: B=4, N=2048, D=1024, H=16, hd=64, NCTX=512
#define BATCH  4
#define NSEQ   2048
#define DMODEL 1024
#define NHEAD  16
#define HDIM   64
#define NCTXC  512

typedef unsigned short u16;
typedef __attribute__((ext_vector_type(8))) short bfrag;   // 8 bf16 = 4 VGPRs (MFMA A/B operand)
typedef __attribute__((ext_vector_type(4))) float facc;    // MFMA C/D operand

typedef __attribute__((address_space(3))) void lds_void;
typedef __attribute__((address_space(1))) void g_void;

__device__ __forceinline__ void gload16(const void* g, void* l) {
  __builtin_amdgcn_global_load_lds((const g_void*)g, (lds_void*)l, 16, 0, 0);
}

__device__ __forceinline__ u16 f2bf(float f) {
  union { float f; uint32_t u; } un; un.f = f;
  uint32_t u = un.u;
  u += 0x7fffu + ((u >> 16) & 1u);   // RNE
  return (u16)(u >> 16);
}

#if __has_builtin(__builtin_amdgcn_cvt_pk_bf16_f32)
__device__ __forceinline__ uint32_t pk2bf(float a, float b) {
  return __builtin_bit_cast(uint32_t, __builtin_amdgcn_cvt_pk_bf16_f32(a, b));
}
#else
__device__ __forceinline__ uint32_t pk2bf(float a, float b) {
  return (uint32_t)f2bf(a) | ((uint32_t)f2bf(b) << 16);
}
#endif

__device__ __forceinline__ float bf2f(u16 h) {
  union { uint32_t u; float f; } un;
  un.u = ((uint32_t)h) << 16;
  return un.f;
}

__device__ __forceinline__ float load_flex(const void* p, size_t idx, int isb) {
  return isb ? bf2f(((const u16*)p)[idx]) : ((const float*)p)[idx];
}

__device__ __forceinline__ uint4 pack8(float4 a, float4 b) {
  uint4 r;
  r.x = pk2bf(a.x, a.y);
  r.y = pk2bf(a.z, a.w);
  r.z = pk2bf(b.x, b.y);
  r.w = pk2bf(b.z, b.w);
  return r;
}

// ---------------------------------------------------------------- dtype detector
__global__ __launch_bounds__(256) void detect_kernel(const u16* __restrict__ xraw,
                                                     int* __restrict__ flag) {
  __shared__ int s_high, s_zero;
  if (threadIdx.x == 0) { s_high = 0; s_zero = 0; }
  __syncthreads();
  int h = 0, z = 0;
  for (int i = threadIdx.x; i < 4096; i += 256) {
    const u16 v = xraw[2 * i];
    const int e = (v >> 7) & 0xFF;
    if (e >= 0x90) h++;
    if (v == 0) z++;
  }
  atomicAdd(&s_high, h);
  atomicAdd(&s_zero, z);
  __syncthreads();
  if (threadIdx.x == 0) flag[0] = (s_high < 64 && s_zero < 2048) ? 1 : 0;
}

// ---------------------------------------------------------------- prep kernels

__global__ __launch_bounds__(256) void cast_x_kernel(const void* __restrict__ x,
                                                     u16* __restrict__ xb,
                                                     const int* __restrict__ flag) {
  const int isb = flag[0];
  const int i = blockIdx.x * 256 + threadIdx.x;
  if (isb) {
    ((uint4*)xb)[i] = ((const uint4*)x)[i];
  } else {
    const float4 f0 = ((const float4*)x)[2 * i];
    const float4 f1 = ((const float4*)x)[2 * i + 1];
    ((uint4*)xb)[i] = pack8(f0, f1);
  }
}

__global__ __launch_bounds__(256) void transpose_flex(const void* __restrict__ W,
                                                      u16* __restrict__ Wt,
                                                      int R, int C,
                                                      const int* __restrict__ flag) {
  __shared__ float tile[32][33];
  const int isb = flag[0];
  const int tx = threadIdx.x;
  const int ty = threadIdx.y;
  const int c0 = blockIdx.x * 32;
  const int r0 = blockIdx.y * 32;
#pragma unroll
  for (int j = 0; j < 32; j += 8)
    tile[ty + j][tx] = load_flex(W, (size_t)(r0 + ty + j) * C + c0 + tx, isb);
  __syncthreads();
#pragma unroll
  for (int j = 0; j < 32; j += 8)
    Wt[(size_t)(c0 + ty + j) * R + r0 + tx] = f2bf(tile[tx][ty + j]);
}

// fused small preps; cbias pre-scaled by log2(e) for exp2-domain softmax
__global__ __launch_bounds__(256) void prep_small(const void* __restrict__ b_in,
                                                  const void* __restrict__ b_out,
                                                  const void* __restrict__ ppr,
                                                  const void* __restrict__ trust,
                                                  const void* __restrict__ alpha_p,
                                                  const void* __restrict__ ts_p,
                                                  float* __restrict__ bin_f,
                                                  float* __restrict__ bout_f,
                                                  float* __restrict__ gate,
                                                  float* __restrict__ cbias,
                                                  const int* __restrict__ flag) {
  const int isb = flag[0];
  const int i = blockIdx.x * 256 + threadIdx.x;
  if (i < 3072) {
    bin_f[i] = load_flex(b_in, i, isb);
  } else if (i < 4096) {
    bout_f[i - 3072] = load_flex(b_out, i - 3072, isb);
  } else if (i < 4096 + BATCH * NCTXC) {
    const int j = i - 4096;
    const float ts = load_flex(ts_p, 0, isb), al = load_flex(alpha_p, 0, isb);
    gate[j]  = 1.0f / (1.0f + __expf(-ts * load_flex(trust, j, isb)));
    cbias[j] = -al * logf(fmaxf(load_flex(ppr, j, isb), 1e-8f)) * 1.44269504f;
  }
}

// ---------------------------------------------------------------- shared K-loop (m97 staging)
__device__ __forceinline__ void kloop_mfma(const u16* __restrict__ Ag,
                                           const u16* __restrict__ Bg,
                                           u16* As, u16* Bs,
                                           int tid, int wM, int wN, int l16, int quad,
                                           facc acc[4][4]) {
  char* ldsA = (char*)As + tid * 16;
  char* ldsB = (char*)Bs + tid * 16;
  for (int k0 = 0; k0 < 1024; k0 += 32) {
    __syncthreads();
    gload16(Ag + k0, ldsA);
    gload16(Ag + (size_t)64 * 1024 + k0, ldsA + 4096);
    gload16(Bg + k0, ldsB);
    gload16(Bg + (size_t)64 * 1024 + k0, ldsB + 4096);
    __syncthreads();

    bfrag af[4], bf[4];
#pragma unroll
    for (int i = 0; i < 4; ++i)
      af[i] = *(const bfrag*)(&As[(wM + i * 16 + l16) * 32 + quad * 8]);
#pragma unroll
    for (int j = 0; j < 4; ++j)
      bf[j] = *(const bfrag*)(&Bs[(wN + j * 16 + l16) * 32 + quad * 8]);
#pragma unroll
    for (int i = 0; i < 4; ++i)
#pragma unroll
      for (int j = 0; j < 4; ++j)
        acc[i][j] = __builtin_amdgcn_mfma_f32_16x16x32_bf16(af[i], bf[j], acc[i][j], 0, 0, 0);
  }
}

// ---------------------------------------------------------------- merged QK + V^T GEMM
__global__ __launch_bounds__(256) void gemm_qkvt(const u16* __restrict__ xb,
                                                 const u16* __restrict__ Wt,
                                                 const float* __restrict__ bin_f,
                                                 const float* __restrict__ gate,
                                                 u16* __restrict__ qk,
                                                 u16* __restrict__ Vtg) {
  __shared__ u16 As[128 * 32];
  __shared__ u16 Bs[128 * 32];
  const int tid  = threadIdx.x;
  const int w    = tid >> 6;
  const int lane = tid & 63;
  const int quad = lane >> 4;
  const int l16  = lane & 15;
  const int wM   = (w >> 1) * 64;
  const int wN   = (w & 1) * 64;
  const int id   = blockIdx.x;
  const int srow  = tid >> 2;
  const int spart = tid & 3;

  facc acc[4][4] = {};

  if (id < 1024) {
    const int bn = id & 15, bm = id >> 4;
    const u16* Ag = xb + (size_t)(bm * 128 + srow) * 1024 + spart * 8;
    const u16* Bg = Wt + (size_t)(bn * 128 + srow) * 1024 + spart * 8;
    kloop_mfma(Ag, Bg, As, Bs, tid, wM, wN, l16, quad, acc);

    const float qs = (bn < 8) ? 0.18033688f : 1.0f;
#pragma unroll
    for (int i = 0; i < 4; ++i) {
      const int grow0 = bm * 128 + wM + i * 16 + quad * 4;
#pragma unroll
      for (int j = 0; j < 4; ++j) {
        const int gcol = bn * 128 + wN + j * 16 + l16;
        const float bv = bin_f[gcol];
#pragma unroll
        for (int r = 0; r < 4; ++r)
          qk[(size_t)(grow0 + r) * 2048 + gcol] = f2bf((acc[i][j][r] + bv) * qs);
      }
    }
  } else {
    const int id2 = id - 1024;
    const int bn = id2 & 63, bm = id2 >> 6;
    const u16* Ag = Wt + (size_t)2048 * 1024 + (size_t)(bm * 128 + srow) * 1024 + spart * 8;
    const u16* Bg = xb + (size_t)(bn * 128 + srow) * 1024 + spart * 8;
    kloop_mfma(Ag, Bg, As, Bs, tid, wM, wN, l16, quad, acc);

#pragma unroll
    for (int i = 0; i < 4; ++i) {
      const int grow0 = bm * 128 + wM + i * 16 + quad * 4;
      const int h   = grow0 >> 6;
      const int dd0 = grow0 & 63;
#pragma unroll
      for (int j = 0; j < 4; ++j) {
        const int gcol = bn * 128 + wN + j * 16 + l16;
        const int bb  = gcol >> 11;
        const int tok = gcol & (NSEQ - 1);
        const float gl = (tok < NCTXC) ? gate[bb * NCTXC + tok] : 1.0f;
        u16* dst = &Vtg[((size_t)((bb * NHEAD + h) * HDIM + dd0)) * NSEQ + tok];
#pragma unroll
        for (int r = 0; r < 4; ++r)
          dst[(size_t)r * NSEQ] = f2bf((acc[i][j][r] + bin_f[2 * DMODEL + grow0 + r]) * gl);
      }
    }
  }
}

// ---------------------------------------------------------------- output GEMM (m97 staging)
__global__ __launch_bounds__(256) void gemm_out(const u16* __restrict__ A,
                                                const u16* __restrict__ Bt,
                                                const float* __restrict__ biasf,
                                                void* __restrict__ Cout,
                                                const int* __restrict__ flag) {
  __shared__ u16 As[128 * 32];
  __shared__ u16 Bs[128 * 32];
  const int isb  = flag[0];
  const int tid  = threadIdx.x;
  const int w    = tid >> 6;
  const int lane = tid & 63;
  const int quad = lane >> 4;
  const int l16  = lane & 15;
  const int wM   = (w >> 1) * 64;
  const int wN   = (w & 1) * 64;
  const int bm   = blockIdx.y;
  const int bn   = blockIdx.x;
  const int srow  = tid >> 2;
  const int spart = tid & 3;

  facc acc[4][4] = {};
  const u16* Ag = A + (size_t)(bm * 128 + srow) * 2048 + spart * 8;
  const u16* Bg = Bt + (size_t)(bn * 128 + srow) * 1024 + spart * 8;
  char* ldsA = (char*)As + tid * 16;
  char* ldsB = (char*)Bs + tid * 16;

  for (int k0 = 0; k0 < 1024; k0 += 32) {
    __syncthreads();
    gload16(Ag + k0, ldsA);
    gload16(Ag + (size_t)64 * 2048 + k0, ldsA + 4096);
    gload16(Bg + k0, ldsB);
    gload16(Bg + (size_t)64 * 1024 + k0, ldsB + 4096);
    __syncthreads();

    bfrag af[4], bf[4];
#pragma unroll
    for (int i = 0; i < 4; ++i)
      af[i] = *(const bfrag*)(&As[(wM + i * 16 + l16) * 32 + quad * 8]);
#pragma unroll
    for (int j = 0; j < 4; ++j)
      bf[j] = *(const bfrag*)(&Bs[(wN + j * 16 + l16) * 32 + quad * 8]);
#pragma unroll
    for (int i = 0; i < 4; ++i)
#pragma unroll
      for (int j = 0; j < 4; ++j)
        acc[i][j] = __builtin_amdgcn_mfma_f32_16x16x32_bf16(af[i], bf[j], acc[i][j], 0, 0, 0);
  }

#pragma unroll
  for (int i = 0; i < 4; ++i) {
    const int grow0 = bm * 128 + wM + i * 16 + quad * 4;
#pragma unroll
    for (int j = 0; j < 4; ++j) {
      const int gcol = bn * 128 + wN + j * 16 + l16;
      const float bv = biasf[gcol];
#pragma unroll
      for (int r = 0; r < 4; ++r) {
        const float v = acc[i][j][r] + bv;
        if (isb) ((u16*)Cout)[(size_t)(grow0 + r) * 1024 + gcol] = f2bf(v);
        else     ((float*)Cout)[(size_t)(grow0 + r) * 1024 + gcol] = v;
      }
    }
  }
}

// ---------------------------------------------------------------- flash attention
// 128-q blocks, S^T form, static softmax (exp2 domain), K/V prefetch, K+V frags in regs.
// XCD-AWARE SWIZZLE: flat grid 1024; decode so the 16 q-tiles of one (b,h) share a
// mod-8 residue (= same XCD under round-robin dispatch) -> each head's 0.5 MB K/V
// plane is fetched by ONE XCD and stays L2-resident instead of being streamed by all 8.
__global__ __launch_bounds__(256) void attn_kernel(u16* __restrict__ qk,
                                                   const u16* __restrict__ vtg,
                                                   const float* __restrict__ cbias) {
  const int id    = blockIdx.x;             // 0..1023
  const int chunk = id >> 3;                // 0..127
  const int qt    = chunk & 15;             // q-tile within head
  const int hg    = (id & 7) | ((chunk >> 4) << 3);   // head-group 0..63
  const int h     = hg & 15;
  const int b     = hg >> 4;

  __shared__ u16 Ks[64 * 72];        // K tile [kv][d]
  __shared__ u16 Vt[64 * 72];        // V^T tile [d][kv]
  __shared__ u16 Ps[4 * 16 * 72];    // per-wave P [q16][kv], wave-private

  const int tid  = threadIdx.x;
  const int w    = tid >> 6;
  const int lane = tid & 63;
  const int quad = lane >> 4;
  const int l16  = lane & 15;
  const int srow = tid >> 2;
  const int spart = tid & 3;

  // Q fragments for both subtiles (Q pre-scaled into exp2 domain by GEMM epilogue)
  bfrag bq[2][2];
#pragma unroll
  for (int qs = 0; qs < 2; ++qs) {
    const u16* qrow = qk + (size_t)(b * NSEQ + qt * 128 + (w * 2 + qs) * 16 + l16) * 2048 + h * HDIM;
    bq[qs][0] = *(const bfrag*)(qrow + quad * 8);
    bq[qs][1] = *(const bfrag*)(qrow + 32 + quad * 8);
  }

  float l_i[2] = {0.0f, 0.0f};
  facc o[2][4] = {};

  const u16* kst = qk + (size_t)(b * NSEQ) * 2048 + DMODEL + h * HDIM;
  const u16* vst = vtg + (size_t)((b * NHEAD + h) * HDIM + srow) * NSEQ;
  u16* psw = &Ps[w * 16 * 72];

  uint4 pk0, pk1, pv0, pv1;
  {
    const u16* ks = kst + (size_t)srow * 2048 + spart * 16;
    pk0 = *(const uint4*)ks;
    pk1 = *(const uint4*)(ks + 8);
    const u16* vs = vst + spart * 16;
    pv0 = *(const uint4*)vs;
    pv1 = *(const uint4*)(vs + 8);
  }

  for (int t = 0; t < NSEQ / 64; ++t) {
    __syncthreads();
    *(uint4*)(&Ks[srow * 72 + spart * 16])     = pk0;
    *(uint4*)(&Ks[srow * 72 + spart * 16 + 8]) = pk1;
    *(uint4*)(&Vt[srow * 72 + spart * 16])     = pv0;
    *(uint4*)(&Vt[srow * 72 + spart * 16 + 8]) = pv1;
    __syncthreads();

    // prefetch next K/V tile
    {
      const int tn = (t < NSEQ / 64 - 1) ? t + 1 : t;
      const u16* ks = kst + (size_t)(tn * 64 + srow) * 2048 + spart * 16;
      pk0 = *(const uint4*)ks;
      pk1 = *(const uint4*)(ks + 8);
      const u16* vs = vst + tn * 64 + spart * 16;
      pv0 = *(const uint4*)vs;
      pv1 = *(const uint4*)(vs + 8);
    }

    // K and V fragments once per tile, held across both q-subtiles
    bfrag ak[4][2], av[4][2];
#pragma unroll
    for (int nt = 0; nt < 4; ++nt) {
      ak[nt][0] = *(const bfrag*)(&Ks[(nt * 16 + l16) * 72 + quad * 8]);
      ak[nt][1] = *(const bfrag*)(&Ks[(nt * 16 + l16) * 72 + 32 + quad * 8]);
      av[nt][0] = *(const bfrag*)(&Vt[(nt * 16 + l16) * 72 + quad * 8]);
      av[nt][1] = *(const bfrag*)(&Vt[(nt * 16 + l16) * 72 + 32 + quad * 8]);
    }

#pragma unroll
    for (int qs = 0; qs < 2; ++qs) {
      facc s[4];
#pragma unroll
      for (int nt = 0; nt < 4; ++nt) {
        facc z = {};
        z = __builtin_amdgcn_mfma_f32_16x16x32_bf16(ak[nt][0], bq[qs][0], z, 0, 0, 0);
        s[nt] = __builtin_amdgcn_mfma_f32_16x16x32_bf16(ak[nt][1], bq[qs][1], z, 0, 0, 0);
      }

      // static softmax: p = exp2(s [+ cbias_pre]); kv = t*64+nt*16+quad*4+r
      float rs = 0.0f;
      if (t < 8) {
        const float* cb = cbias + b * NCTXC + t * 64 + quad * 4;
#pragma unroll
        for (int nt = 0; nt < 4; ++nt)
#pragma unroll
          for (int r = 0; r < 4; ++r) {
            const float p = __builtin_amdgcn_exp2f(s[nt][r] + cb[nt * 16 + r]);
            s[nt][r] = p;
            rs += p;
          }
      } else {
#pragma unroll
        for (int nt = 0; nt < 4; ++nt)
#pragma unroll
          for (int r = 0; r < 4; ++r) {
            const float p = __builtin_amdgcn_exp2f(s[nt][r]);
            s[nt][r] = p;
            rs += p;
          }
      }
      rs += __shfl_xor(rs, 16);
      rs += __shfl_xor(rs, 32);
      l_i[qs] += rs;

      // P -> wave-private Ps (in-order DS pipe keeps read-before-write across qs)
#pragma unroll
      for (int nt = 0; nt < 4; ++nt) {
        uint2 pk;
        pk.x = pk2bf(s[nt][0], s[nt][1]);
        pk.y = pk2bf(s[nt][2], s[nt][3]);
        *(uint2*)(&psw[l16 * 72 + nt * 16 + quad * 4]) = pk;
      }

      __asm__ volatile("s_waitcnt lgkmcnt(0)" ::: "memory");

      const bfrag bp0 = *(const bfrag*)(&psw[l16 * 72 + quad * 8]);
      const bfrag bp1 = *(const bfrag*)(&psw[l16 * 72 + 32 + quad * 8]);
#pragma unroll
      for (int dt = 0; dt < 4; ++dt) {
        o[qs][dt] = __builtin_amdgcn_mfma_f32_16x16x32_bf16(av[dt][0], bp0, o[qs][dt], 0, 0, 0);
        o[qs][dt] = __builtin_amdgcn_mfma_f32_16x16x32_bf16(av[dt][1], bp1, o[qs][dt], 0, 0, 0);
      }
    }
  }

  // O^T C-layout: col=l16=q, row=quad*4+r=d -> pack 4 consecutive d
#pragma unroll
  for (int qs = 0; qs < 2; ++qs) {
    const float inv = 1.0f / l_i[qs];
    u16* orow = qk + (size_t)(b * NSEQ + qt * 128 + (w * 2 + qs) * 16 + l16) * 2048 + h * HDIM;
#pragma unroll
    for (int dt = 0; dt < 4; ++dt) {
      uint2 st;
      st.x = pk2bf(o[qs][dt][0] * inv, o[qs][dt][1] * inv);
      st.y = pk2bf(o[qs][dt][2] * inv, o[qs][dt][3] * inv);
      *(uint2*)(orow + dt * 16 + quad * 4) = st;
    }
  }
}

// ---------------------------------------------------------------- launch

extern "C" void kernel_launch(void* const* d_in, const int* in_sizes, int n_in,
                              void* d_out, int out_size, void* d_ws, size_t ws_size,
                              hipStream_t stream) {
  const void* x          = d_in[0];
  const void* ctx_ppr    = d_in[1];
  const void* ctx_trust  = d_in[2];
  const void* W_in       = d_in[3];
  const void* b_in       = d_in[4];
  const void* W_out      = d_in[5];
  const void* b_out      = d_in[6];
  const void* lppr_alpha = d_in[7];
  const void* tscale     = d_in[8];

  char* ws = (char*)d_ws;
  u16* Wt    = (u16*)ws;  ws += (size_t)3072 * 1024 * 2;    //  6 MB  W_in^T bf16
  u16* WoT   = (u16*)ws;  ws += (size_t)1024 * 1024 * 2;    //  2 MB  W_out^T bf16
  u16* qk    = (u16*)ws;  ws += (size_t)8192 * 2048 * 2;    // 32 MB  [Q|K]; attn-out overwrites Q-plane
  u16* Vtg   = (u16*)ws;  ws += (size_t)64 * 64 * 2048 * 2; // 16 MB  gated V^T [b*16+h][d][n]
  u16* xb    = (u16*)ws;  ws += (size_t)8192 * 1024 * 2;    // 16 MB  x as bf16
  float* bin_f  = (float*)ws; ws += 3072 * 4;
  float* bout_f = (float*)ws; ws += 1024 * 4;
  float* gate   = (float*)ws; ws += (size_t)BATCH * NCTXC * 4;
  float* cbias  = (float*)ws; ws += (size_t)BATCH * NCTXC * 4;
  int*   flag   = (int*)ws;   ws += 64;

  detect_kernel<<<dim3(1), dim3(256), 0, stream>>>((const u16*)x, flag);
  cast_x_kernel<<<dim3(4096), dim3(256), 0, stream>>>(x, xb, flag);
  transpose_flex<<<dim3(96, 32), dim3(32, 8), 0, stream>>>(W_in, Wt, 1024, 3072, flag);
  transpose_flex<<<dim3(32, 32), dim3(32, 8), 0, stream>>>(W_out, WoT, 1024, 1024, flag);
  prep_small<<<dim3(24), dim3(256), 0, stream>>>(b_in, b_out, ctx_ppr, ctx_trust,
                                                 lppr_alpha, tscale,
                                                 bin_f, bout_f, gate, cbias, flag);
  // merged QK GEMM (1024 blocks) + V^T GEMM (512 blocks)
  gemm_qkvt<<<dim3(1536), dim3(256), 0, stream>>>(xb, Wt, bin_f, gate, qk, Vtg);
  // fused biased attention (128-q blocks, XCD-swizzled), output into qk Q-plane
  attn_kernel<<<dim3(1024), dim3(256), 0, stream>>>(qk, Vtg, cbias);
  // output GEMM: [8192x1024 (lda 2048)] @ [1024x1024] (+b_out) -> d_out
  gemm_out<<<dim3(8, 64), dim3(256), 0, stream>>>(qk, WoT, bout_f, d_out, flag);
}

// Round 13
// 319.886 us; speedup vs baseline: 1.1430x; 1.0446x over previous
//
#include <hip/hip_runtime.h>
#include <hip/hip_bf16.h>
#include <stdint.h>

// Problem constants: B=4, N=2048, D=1024, H=16, hd=64, NCTX=512
#define BATCH  4
#define NSEQ   2048
#define DMODEL 1024
#define NHEAD  16
#define HDIM   64
#define NCTXC  512

typedef unsigned short u16;
typedef __attribute__((ext_vector_type(8))) short bfrag;   // 8 bf16 = 4 VGPRs (MFMA A/B operand)
typedef __attribute__((ext_vector_type(4))) float facc;    // MFMA C/D operand

typedef __attribute__((address_space(3))) void lds_void;
typedef __attribute__((address_space(1))) void g_void;

__device__ __forceinline__ void gload16(const void* g, void* l) {
  __builtin_amdgcn_global_load_lds((const g_void*)g, (lds_void*)l, 16, 0, 0);
}

__device__ __forceinline__ u16 f2bf(float f) {
  union { float f; uint32_t u; } un; un.f = f;
  uint32_t u = un.u;
  u += 0x7fffu + ((u >> 16) & 1u);   // RNE
  return (u16)(u >> 16);
}

#if __has_builtin(__builtin_amdgcn_cvt_pk_bf16_f32)
__device__ __forceinline__ uint32_t pk2bf(float a, float b) {
  return __builtin_bit_cast(uint32_t, __builtin_amdgcn_cvt_pk_bf16_f32(a, b));
}
#else
__device__ __forceinline__ uint32_t pk2bf(float a, float b) {
  return (uint32_t)f2bf(a) | ((uint32_t)f2bf(b) << 16);
}
#endif

__device__ __forceinline__ float bf2f(u16 h) {
  union { uint32_t u; float f; } un;
  un.u = ((uint32_t)h) << 16;
  return un.f;
}

__device__ __forceinline__ float load_flex(const void* p, size_t idx, int isb) {
  return isb ? bf2f(((const u16*)p)[idx]) : ((const float*)p)[idx];
}

__device__ __forceinline__ uint4 pack8(float4 a, float4 b) {
  uint4 r;
  r.x = pk2bf(a.x, a.y);
  r.y = pk2bf(a.z, a.w);
  r.z = pk2bf(b.x, b.y);
  r.w = pk2bf(b.z, b.w);
  return r;
}

// ---------------------------------------------------------------- dtype detector
__global__ __launch_bounds__(256) void detect_kernel(const u16* __restrict__ xraw,
                                                     int* __restrict__ flag) {
  __shared__ int s_high, s_zero;
  if (threadIdx.x == 0) { s_high = 0; s_zero = 0; }
  __syncthreads();
  int h = 0, z = 0;
  for (int i = threadIdx.x; i < 4096; i += 256) {
    const u16 v = xraw[2 * i];
    const int e = (v >> 7) & 0xFF;
    if (e >= 0x90) h++;
    if (v == 0) z++;
  }
  atomicAdd(&s_high, h);
  atomicAdd(&s_zero, z);
  __syncthreads();
  if (threadIdx.x == 0) flag[0] = (s_high < 64 && s_zero < 2048) ? 1 : 0;
}

// ---------------------------------------------------------------- prep kernels

__global__ __launch_bounds__(256) void cast_x_kernel(const void* __restrict__ x,
                                                     u16* __restrict__ xb,
                                                     const int* __restrict__ flag) {
  const int isb = flag[0];
  const int i = blockIdx.x * 256 + threadIdx.x;
  if (isb) {
    ((uint4*)xb)[i] = ((const uint4*)x)[i];
  } else {
    const float4 f0 = ((const float4*)x)[2 * i];
    const float4 f1 = ((const float4*)x)[2 * i + 1];
    ((uint4*)xb)[i] = pack8(f0, f1);
  }
}

__global__ __launch_bounds__(256) void transpose_flex(const void* __restrict__ W,
                                                      u16* __restrict__ Wt,
                                                      int R, int C,
                                                      const int* __restrict__ flag) {
  __shared__ float tile[32][33];
  const int isb = flag[0];
  const int tx = threadIdx.x;
  const int ty = threadIdx.y;
  const int c0 = blockIdx.x * 32;
  const int r0 = blockIdx.y * 32;
#pragma unroll
  for (int j = 0; j < 32; j += 8)
    tile[ty + j][tx] = load_flex(W, (size_t)(r0 + ty + j) * C + c0 + tx, isb);
  __syncthreads();
#pragma unroll
  for (int j = 0; j < 32; j += 8)
    Wt[(size_t)(c0 + ty + j) * R + r0 + tx] = f2bf(tile[tx][ty + j]);
}

// fused small preps; cbias pre-scaled by log2(e) for exp2-domain softmax
__global__ __launch_bounds__(256) void prep_small(const void* __restrict__ b_in,
                                                  const void* __restrict__ b_out,
                                                  const void* __restrict__ ppr,
                                                  const void* __restrict__ trust,
                                                  const void* __restrict__ alpha_p,
                                                  const void* __restrict__ ts_p,
                                                  float* __restrict__ bin_f,
                                                  float* __restrict__ bout_f,
                                                  float* __restrict__ gate,
                                                  float* __restrict__ cbias,
                                                  const int* __restrict__ flag) {
  const int isb = flag[0];
  const int i = blockIdx.x * 256 + threadIdx.x;
  if (i < 3072) {
    bin_f[i] = load_flex(b_in, i, isb);
  } else if (i < 4096) {
    bout_f[i - 3072] = load_flex(b_out, i - 3072, isb);
  } else if (i < 4096 + BATCH * NCTXC) {
    const int j = i - 4096;
    const float ts = load_flex(ts_p, 0, isb), al = load_flex(alpha_p, 0, isb);
    gate[j]  = 1.0f / (1.0f + __expf(-ts * load_flex(trust, j, isb)));
    cbias[j] = -al * logf(fmaxf(load_flex(ppr, j, isb), 1e-8f)) * 1.44269504f;
  }
}

// ---------------------------------------------------------------- shared K-loop (m97 staging)
__device__ __forceinline__ void kloop_mfma(const u16* __restrict__ Ag,
                                           const u16* __restrict__ Bg,
                                           u16* As, u16* Bs,
                                           int tid, int wM, int wN, int l16, int quad,
                                           facc acc[4][4]) {
  char* ldsA = (char*)As + tid * 16;
  char* ldsB = (char*)Bs + tid * 16;
  for (int k0 = 0; k0 < 1024; k0 += 32) {
    __syncthreads();
    gload16(Ag + k0, ldsA);
    gload16(Ag + (size_t)64 * 1024 + k0, ldsA + 4096);
    gload16(Bg + k0, ldsB);
    gload16(Bg + (size_t)64 * 1024 + k0, ldsB + 4096);
    __syncthreads();

    bfrag af[4], bf[4];
#pragma unroll
    for (int i = 0; i < 4; ++i)
      af[i] = *(const bfrag*)(&As[(wM + i * 16 + l16) * 32 + quad * 8]);
#pragma unroll
    for (int j = 0; j < 4; ++j)
      bf[j] = *(const bfrag*)(&Bs[(wN + j * 16 + l16) * 32 + quad * 8]);
#pragma unroll
    for (int i = 0; i < 4; ++i)
#pragma unroll
      for (int j = 0; j < 4; ++j)
        acc[i][j] = __builtin_amdgcn_mfma_f32_16x16x32_bf16(af[i], bf[j], acc[i][j], 0, 0, 0);
  }
}

// ---------------------------------------------------------------- merged QK + V^T GEMM
__global__ __launch_bounds__(256) void gemm_qkvt(const u16* __restrict__ xb,
                                                 const u16* __restrict__ Wt,
                                                 const float* __restrict__ bin_f,
                                                 const float* __restrict__ gate,
                                                 u16* __restrict__ qk,
                                                 u16* __restrict__ Vtg) {
  __shared__ u16 As[128 * 32];
  __shared__ u16 Bs[128 * 32];
  const int tid  = threadIdx.x;
  const int w    = tid >> 6;
  const int lane = tid & 63;
  const int quad = lane >> 4;
  const int l16  = lane & 15;
  const int wM   = (w >> 1) * 64;
  const int wN   = (w & 1) * 64;
  const int id   = blockIdx.x;
  const int srow  = tid >> 2;
  const int spart = tid & 3;

  facc acc[4][4] = {};

  if (id < 1024) {
    const int bn = id & 15, bm = id >> 4;
    const u16* Ag = xb + (size_t)(bm * 128 + srow) * 1024 + spart * 8;
    const u16* Bg = Wt + (size_t)(bn * 128 + srow) * 1024 + spart * 8;
    kloop_mfma(Ag, Bg, As, Bs, tid, wM, wN, l16, quad, acc);

    const float qs = (bn < 8) ? 0.18033688f : 1.0f;
#pragma unroll
    for (int i = 0; i < 4; ++i) {
      const int grow0 = bm * 128 + wM + i * 16 + quad * 4;
#pragma unroll
      for (int j = 0; j < 4; ++j) {
        const int gcol = bn * 128 + wN + j * 16 + l16;
        const float bv = bin_f[gcol];
#pragma unroll
        for (int r = 0; r < 4; ++r)
          qk[(size_t)(grow0 + r) * 2048 + gcol] = f2bf((acc[i][j][r] + bv) * qs);
      }
    }
  } else {
    const int id2 = id - 1024;
    const int bn = id2 & 63, bm = id2 >> 6;
    const u16* Ag = Wt + (size_t)2048 * 1024 + (size_t)(bm * 128 + srow) * 1024 + spart * 8;
    const u16* Bg = xb + (size_t)(bn * 128 + srow) * 1024 + spart * 8;
    kloop_mfma(Ag, Bg, As, Bs, tid, wM, wN, l16, quad, acc);

#pragma unroll
    for (int i = 0; i < 4; ++i) {
      const int grow0 = bm * 128 + wM + i * 16 + quad * 4;
      const int h   = grow0 >> 6;
      const int dd0 = grow0 & 63;
#pragma unroll
      for (int j = 0; j < 4; ++j) {
        const int gcol = bn * 128 + wN + j * 16 + l16;
        const int bb  = gcol >> 11;
        const int tok = gcol & (NSEQ - 1);
        const float gl = (tok < NCTXC) ? gate[bb * NCTXC + tok] : 1.0f;
        u16* dst = &Vtg[((size_t)((bb * NHEAD + h) * HDIM + dd0)) * NSEQ + tok];
#pragma unroll
        for (int r = 0; r < 4; ++r)
          dst[(size_t)r * NSEQ] = f2bf((acc[i][j][r] + bin_f[2 * DMODEL + grow0 + r]) * gl);
      }
    }
  }
}

// ---------------------------------------------------------------- output GEMM (m97 staging)
__global__ __launch_bounds__(256) void gemm_out(const u16* __restrict__ A,
                                                const u16* __restrict__ Bt,
                                                const float* __restrict__ biasf,
                                                void* __restrict__ Cout,
                                                const int* __restrict__ flag) {
  __shared__ u16 As[128 * 32];
  __shared__ u16 Bs[128 * 32];
  const int isb  = flag[0];
  const int tid  = threadIdx.x;
  const int w    = tid >> 6;
  const int lane = tid & 63;
  const int quad = lane >> 4;
  const int l16  = lane & 15;
  const int wM   = (w >> 1) * 64;
  const int wN   = (w & 1) * 64;
  const int bm   = blockIdx.y;
  const int bn   = blockIdx.x;
  const int srow  = tid >> 2;
  const int spart = tid & 3;

  facc acc[4][4] = {};
  const u16* Ag = A + (size_t)(bm * 128 + srow) * 2048 + spart * 8;
  const u16* Bg = Bt + (size_t)(bn * 128 + srow) * 1024 + spart * 8;
  char* ldsA = (char*)As + tid * 16;
  char* ldsB = (char*)Bs + tid * 16;

  for (int k0 = 0; k0 < 1024; k0 += 32) {
    __syncthreads();
    gload16(Ag + k0, ldsA);
    gload16(Ag + (size_t)64 * 2048 + k0, ldsA + 4096);
    gload16(Bg + k0, ldsB);
    gload16(Bg + (size_t)64 * 1024 + k0, ldsB + 4096);
    __syncthreads();

    bfrag af[4], bf[4];
#pragma unroll
    for (int i = 0; i < 4; ++i)
      af[i] = *(const bfrag*)(&As[(wM + i * 16 + l16) * 32 + quad * 8]);
#pragma unroll
    for (int j = 0; j < 4; ++j)
      bf[j] = *(const bfrag*)(&Bs[(wN + j * 16 + l16) * 32 + quad * 8]);
#pragma unroll
    for (int i = 0; i < 4; ++i)
#pragma unroll
      for (int j = 0; j < 4; ++j)
        acc[i][j] = __builtin_amdgcn_mfma_f32_16x16x32_bf16(af[i], bf[j], acc[i][j], 0, 0, 0);
  }

#pragma unroll
  for (int i = 0; i < 4; ++i) {
    const int grow0 = bm * 128 + wM + i * 16 + quad * 4;
#pragma unroll
    for (int j = 0; j < 4; ++j) {
      const int gcol = bn * 128 + wN + j * 16 + l16;
      const float bv = biasf[gcol];
#pragma unroll
      for (int r = 0; r < 4; ++r) {
        const float v = acc[i][j][r] + bv;
        if (isb) ((u16*)Cout)[(size_t)(grow0 + r) * 1024 + gcol] = f2bf(v);
        else     ((float*)Cout)[(size_t)(grow0 + r) * 1024 + gcol] = v;
      }
    }
  }
}

// ---------------------------------------------------------------- flash attention
// 128-q blocks, S^T form, static softmax, XCD swizzle (R12), and now CHAIN SURGERY:
//  - no forced lgkmcnt(0) drains: per-(wave,qs) private Ps slices; DS in-order
//    completion per wave + compiler waitcnt give read-after-write for free.
//  - body ordered QK0,exp0,W0, QK1,exp1,W1, R0,PV0, R1,PV1 so subtile-1 compute
//    covers subtile-0's P round-trip latency.
//  - softmax denominator: per-lane partials in the loop; single shuffle-reduce
//    in the epilogue (removes 128 serialized DS-shuffle ops per wave).
__global__ __launch_bounds__(256) void attn_kernel(u16* __restrict__ qk,
                                                   const u16* __restrict__ vtg,
                                                   const float* __restrict__ cbias) {
  const int id    = blockIdx.x;             // 0..1023
  const int chunk = id >> 3;
  const int qt    = chunk & 15;
  const int hg    = (id & 7) | ((chunk >> 4) << 3);
  const int h     = hg & 15;
  const int b     = hg >> 4;

  __shared__ u16 Ks[64 * 72];        // K tile [kv][d]
  __shared__ u16 Vt[64 * 72];        // V^T tile [d][kv]
  __shared__ u16 Ps[8][16 * 72];     // [wave*2+qs] private P slices

  const int tid  = threadIdx.x;
  const int w    = tid >> 6;
  const int lane = tid & 63;
  const int quad = lane >> 4;
  const int l16  = lane & 15;
  const int srow = tid >> 2;
  const int spart = tid & 3;

  bfrag bq[2][2];
#pragma unroll
  for (int qs = 0; qs < 2; ++qs) {
    const u16* qrow = qk + (size_t)(b * NSEQ + qt * 128 + (w * 2 + qs) * 16 + l16) * 2048 + h * HDIM;
    bq[qs][0] = *(const bfrag*)(qrow + quad * 8);
    bq[qs][1] = *(const bfrag*)(qrow + 32 + quad * 8);
  }

  float lp[2] = {0.0f, 0.0f};        // per-lane partial denominators
  facc o[2][4] = {};

  const u16* kst = qk + (size_t)(b * NSEQ) * 2048 + DMODEL + h * HDIM;
  const u16* vst = vtg + (size_t)((b * NHEAD + h) * HDIM + srow) * NSEQ;
  u16* psw[2] = { Ps[w * 2], Ps[w * 2 + 1] };

  uint4 pk0, pk1, pv0, pv1;
  {
    const u16* ks = kst + (size_t)srow * 2048 + spart * 16;
    pk0 = *(const uint4*)ks;
    pk1 = *(const uint4*)(ks + 8);
    const u16* vs = vst + spart * 16;
    pv0 = *(const uint4*)vs;
    pv1 = *(const uint4*)(vs + 8);
  }

  for (int t = 0; t < NSEQ / 64; ++t) {
    __syncthreads();
    *(uint4*)(&Ks[srow * 72 + spart * 16])     = pk0;
    *(uint4*)(&Ks[srow * 72 + spart * 16 + 8]) = pk1;
    *(uint4*)(&Vt[srow * 72 + spart * 16])     = pv0;
    *(uint4*)(&Vt[srow * 72 + spart * 16 + 8]) = pv1;
    __syncthreads();

    // prefetch next K/V tile
    {
      const int tn = (t < NSEQ / 64 - 1) ? t + 1 : t;
      const u16* ks = kst + (size_t)(tn * 64 + srow) * 2048 + spart * 16;
      pk0 = *(const uint4*)ks;
      pk1 = *(const uint4*)(ks + 8);
      const u16* vs = vst + tn * 64 + spart * 16;
      pv0 = *(const uint4*)vs;
      pv1 = *(const uint4*)(vs + 8);
    }

    // K/V fragments once per tile
    bfrag ak[4][2], av[4][2];
#pragma unroll
    for (int nt = 0; nt < 4; ++nt) {
      ak[nt][0] = *(const bfrag*)(&Ks[(nt * 16 + l16) * 72 + quad * 8]);
      ak[nt][1] = *(const bfrag*)(&Ks[(nt * 16 + l16) * 72 + 32 + quad * 8]);
      av[nt][0] = *(const bfrag*)(&Vt[(nt * 16 + l16) * 72 + quad * 8]);
      av[nt][1] = *(const bfrag*)(&Vt[(nt * 16 + l16) * 72 + 32 + quad * 8]);
    }

    // QK(qs) -> exp2 -> Ps write, both subtiles, no drains between
#pragma unroll
    for (int qs = 0; qs < 2; ++qs) {
      facc s[4];
#pragma unroll
      for (int nt = 0; nt < 4; ++nt) {
        facc z = {};
        z = __builtin_amdgcn_mfma_f32_16x16x32_bf16(ak[nt][0], bq[qs][0], z, 0, 0, 0);
        s[nt] = __builtin_amdgcn_mfma_f32_16x16x32_bf16(ak[nt][1], bq[qs][1], z, 0, 0, 0);
      }

      float rs = 0.0f;
      if (t < 8) {
        const float* cb = cbias + b * NCTXC + t * 64 + quad * 4;
#pragma unroll
        for (int nt = 0; nt < 4; ++nt)
#pragma unroll
          for (int r = 0; r < 4; ++r) {
            const float p = __builtin_amdgcn_exp2f(s[nt][r] + cb[nt * 16 + r]);
            s[nt][r] = p;
            rs += p;
          }
      } else {
#pragma unroll
        for (int nt = 0; nt < 4; ++nt)
#pragma unroll
          for (int r = 0; r < 4; ++r) {
            const float p = __builtin_amdgcn_exp2f(s[nt][r]);
            s[nt][r] = p;
            rs += p;
          }
      }
      lp[qs] += rs;                  // per-lane partial; reduced once at the end

#pragma unroll
      for (int nt = 0; nt < 4; ++nt) {
        uint2 pk;
        pk.x = pk2bf(s[nt][0], s[nt][1]);
        pk.y = pk2bf(s[nt][2], s[nt][3]);
        *(uint2*)(&psw[qs][l16 * 72 + nt * 16 + quad * 4]) = pk;
      }
    }

    // P reads + PV, both subtiles (DS in-order => writes above complete first)
#pragma unroll
    for (int qs = 0; qs < 2; ++qs) {
      const bfrag bp0 = *(const bfrag*)(&psw[qs][l16 * 72 + quad * 8]);
      const bfrag bp1 = *(const bfrag*)(&psw[qs][l16 * 72 + 32 + quad * 8]);
#pragma unroll
      for (int dt = 0; dt < 4; ++dt) {
        o[qs][dt] = __builtin_amdgcn_mfma_f32_16x16x32_bf16(av[dt][0], bp0, o[qs][dt], 0, 0, 0);
        o[qs][dt] = __builtin_amdgcn_mfma_f32_16x16x32_bf16(av[dt][1], bp1, o[qs][dt], 0, 0, 0);
      }
    }
  }

  // epilogue: reduce denominators across quads once, normalize, store O^T
#pragma unroll
  for (int qs = 0; qs < 2; ++qs) {
    float l = lp[qs];
    l += __shfl_xor(l, 16);
    l += __shfl_xor(l, 32);
    const float inv = 1.0f / l;
    u16* orow = qk + (size_t)(b * NSEQ + qt * 128 + (w * 2 + qs) * 16 + l16) * 2048 + h * HDIM;
#pragma unroll
    for (int dt = 0; dt < 4; ++dt) {
      uint2 st;
      st.x = pk2bf(o[qs][dt][0] * inv, o[qs][dt][1] * inv);
      st.y = pk2bf(o[qs][dt][2] * inv, o[qs][dt][3] * inv);
      *(uint2*)(orow + dt * 16 + quad * 4) = st;
    }
  }
}

// ---------------------------------------------------------------- launch

extern "C" void kernel_launch(void* const* d_in, const int* in_sizes, int n_in,
                              void* d_out, int out_size, void* d_ws, size_t ws_size,
                              hipStream_t stream) {
  const void* x          = d_in[0];
  const void* ctx_ppr    = d_in[1];
  const void* ctx_trust  = d_in[2];
  const void* W_in       = d_in[3];
  const void* b_in       = d_in[4];
  const void* W_out      = d_in[5];
  const void* b_out      = d_in[6];
  const void* lppr_alpha = d_in[7];
  const void* tscale     = d_in[8];

  char* ws = (char*)d_ws;
  u16* Wt    = (u16*)ws;  ws += (size_t)3072 * 1024 * 2;    //  6 MB  W_in^T bf16
  u16* WoT   = (u16*)ws;  ws += (size_t)1024 * 1024 * 2;    //  2 MB  W_out^T bf16
  u16* qk    = (u16*)ws;  ws += (size_t)8192 * 2048 * 2;    // 32 MB  [Q|K]; attn-out overwrites Q-plane
  u16* Vtg   = (u16*)ws;  ws += (size_t)64 * 64 * 2048 * 2; // 16 MB  gated V^T [b*16+h][d][n]
  u16* xb    = (u16*)ws;  ws += (size_t)8192 * 1024 * 2;    // 16 MB  x as bf16
  float* bin_f  = (float*)ws; ws += 3072 * 4;
  float* bout_f = (float*)ws; ws += 1024 * 4;
  float* gate   = (float*)ws; ws += (size_t)BATCH * NCTXC * 4;
  float* cbias  = (float*)ws; ws += (size_t)BATCH * NCTXC * 4;
  int*   flag   = (int*)ws;   ws += 64;

  detect_kernel<<<dim3(1), dim3(256), 0, stream>>>((const u16*)x, flag);
  cast_x_kernel<<<dim3(4096), dim3(256), 0, stream>>>(x, xb, flag);
  transpose_flex<<<dim3(96, 32), dim3(32, 8), 0, stream>>>(W_in, Wt, 1024, 3072, flag);
  transpose_flex<<<dim3(32, 32), dim3(32, 8), 0, stream>>>(W_out, WoT, 1024, 1024, flag);
  prep_small<<<dim3(24), dim3(256), 0, stream>>>(b_in, b_out, ctx_ppr, ctx_trust,
                                                 lppr_alpha, tscale,
                                                 bin_f, bout_f, gate, cbias, flag);
  // merged QK GEMM (1024 blocks) + V^T GEMM (512 blocks)
  gemm_qkvt<<<dim3(1536), dim3(256), 0, stream>>>(xb, Wt, bin_f, gate, qk, Vtg);
  // fused biased attention (128-q, XCD-swizzled, chain-shortened)
  attn_kernel<<<dim3(1024), dim3(256), 0, stream>>>(qk, Vtg, cbias);
  // output GEMM: [8192x1024 (lda 2048)] @ [1024x1024] (+b_out) -> d_out
  gemm_out<<<dim3(8, 64), dim3(256), 0, stream>>>(qk, WoT, bout_f, d_out, flag);
}